// Round 3
// baseline (477.986 us; speedup 1.0000x reference)
//
#include <hip/hip_runtime.h>

#define Bdim 8
#define Tdim 100
#define Sdim 400
#define Kk   8
#define Hdim 512
#define Vdim 32000
#define Mdim 800          // B*T

typedef __attribute__((ext_vector_type(8))) short short8;     // 8 bf16 = 4 VGPRs
typedef __attribute__((ext_vector_type(4))) float float4_t;   // MFMA acc

static __device__ __forceinline__ unsigned short f2bf(float f) {
    unsigned int x = __float_as_uint(f);
    return (unsigned short)((x + 0x7fffu + ((x >> 16) & 1u)) >> 16);   // RNE
}
static __device__ __forceinline__ float bf2f(unsigned short h) {
    return __uint_as_float(((unsigned int)h) << 16);
}

// async 16B global->LDS (wave-uniform LDS base + lane*16)
static __device__ __forceinline__ void gload_lds16(const void* g, void* s) {
    __builtin_amdgcn_global_load_lds((const __attribute__((address_space(1))) void*)g,
                                     (__attribute__((address_space(3))) void*)s, 16, 0, 0);
}

// ---------------- zero rowsum ----------------
__global__ void zero_kernel(float* __restrict__ p, int n) {
    int i = blockIdx.x * blockDim.x + threadIdx.x;
    if (i < n) p[i] = 0.f;
}

// ---------------- prep: dec_out fp32 -> bf16 in PACKED fragment order ----------------
// Ap[((mt*64 + kc)*16 + l15)*8 + j] = A[mt*16 + l15][kc*8 + j]
// so a wave's A-fragment load (lane = kq*16+l15 reads 16B at base + lane*16) is contiguous.
__global__ void convert_a_kernel(const float* __restrict__ A, unsigned short* __restrict__ Ap) {
    int tid = blockIdx.x * blockDim.x + threadIdx.x;      // 0 .. 50*1024-1
    if (tid >= 50 * 1024) return;
    int mt = tid >> 10;
    int r  = tid & 1023;
    int kc = r >> 4;
    int l15 = r & 15;
    const float* src = A + (size_t)(mt * 16 + l15) * Hdim + kc * 8;
    short8 v;
#pragma unroll
    for (int j = 0; j < 8; ++j) v[j] = (short)f2bf(src[j]);
    *(short8*)(Ap + (size_t)tid * 8) = v;
}

// ---------------- prep: W (512 x 32000) fp32 -> WT (32000 x 512) bf16 ----------------
__global__ void transpose_kernel(const float* __restrict__ W, unsigned short* __restrict__ WT) {
    __shared__ float tile[32][33];
    int k0 = blockIdx.y * 32;
    int v0 = blockIdx.x * 32;
    int tx = threadIdx.x & 31;
    int ty = threadIdx.x >> 5;           // 0..7
#pragma unroll
    for (int i = 0; i < 32; i += 8)
        tile[ty + i][tx] = W[(size_t)(k0 + ty + i) * Vdim + v0 + tx];
    __syncthreads();
#pragma unroll
    for (int i = 0; i < 32; i += 8) {
        int v = v0 + ty + i;
        WT[(size_t)v * Hdim + k0 + tx] = f2bf(tile[tx][ty + i]);
    }
}

// ---------------- GEMM: logits = A * WT^T + bias (bf16 store) + row sumexp ----------------
// One block per 128-col n-stripe (grid=250). B stripe (128x512 bf16 = 131 KB) resident in
// LDS, loaded ONCE via global_load_lds with XOR chunk swizzle. A streamed global->VGPR from
// the packed layout (coalesced 1KB loads, L2-hot). Inner loop barrier-free.
// 4 waves as 2m x 2n, wave tile 64m x 64n; m-loop covers 7 x 128 rows.
__global__ __launch_bounds__(256) void gemm_kernel(const unsigned short* __restrict__ Ap,
                                                   const unsigned short* __restrict__ WT,
                                                   const float* __restrict__ bias,
                                                   unsigned short* __restrict__ logitsbf,
                                                   float* __restrict__ rowsum) {
    __shared__ __align__(16) unsigned short Bs[128 * 512];   // 131072 bytes

    const int tid  = threadIdx.x;
    const int lane = tid & 63;
    const int wave = tid >> 6;
    const int l15  = lane & 15;
    const int kq   = lane >> 4;            // 0..3
    const int n_blk = blockIdx.x * 128;
    const int wm = wave & 1, wn = wave >> 1;
    const int n0 = wn * 64;

    // ---- stage the whole B stripe once (8192 16B chunks, XOR-swizzled low-3 bits) ----
#pragma unroll 4
    for (int it = 0; it < 32; ++it) {
        int s = it * 256 + wave * 64 + lane;              // chunk index
        int row = s >> 6, cs = s & 63;
        int gc = (cs & 56) | ((cs & 7) ^ (row & 7));      // global chunk for this LDS slot
        gload_lds16(WT + (size_t)(n_blk + row) * Hdim + gc * 8,
                    Bs + (size_t)(it * 256 + wave * 64) * 8);
    }
    __syncthreads();

    // B fragment LDS offsets (shorts): n*512 + swizzled_chunk*8
    int e0[4], e1[4];
#pragma unroll
    for (int j = 0; j < 4; ++j) {
        int n = n0 + j * 16 + l15;
        e0[j] = n * 512 + ((kq ^ (n & 7)) * 8);
        e1[j] = n * 512 + (((4 + kq) ^ (n & 7)) * 8);
    }

    float bj[4];
#pragma unroll
    for (int j = 0; j < 4; ++j) bj[j] = bias[n_blk + n0 + j * 16 + l15];

    for (int m_tile = 0; m_tile < 7; ++m_tile) {
        const unsigned short* ap[4];
#pragma unroll
        for (int i = 0; i < 4; ++i) {
            int mt = m_tile * 8 + wm * 4 + i;
            if (mt > 49) mt = 49;                          // clamp; stores masked
            ap[i] = Ap + (size_t)mt * 8192 + lane * 8;
        }

        float4_t acc[4][4] = {};
#pragma unroll
        for (int ks = 0; ks < 16; ++ks) {
            short8 af[4], bfr[4];
#pragma unroll
            for (int i = 0; i < 4; ++i) af[i] = *(const short8*)(ap[i] + ks * 512);
            const int co = (ks >> 1) * 64;
#pragma unroll
            for (int j = 0; j < 4; ++j)
                bfr[j] = *(const short8*)(Bs + ((ks & 1) ? e1[j] : e0[j]) + co);
#pragma unroll
            for (int i = 0; i < 4; ++i)
#pragma unroll
                for (int j = 0; j < 4; ++j)
                    acc[i][j] = __builtin_amdgcn_mfma_f32_16x16x32_bf16(af[i], bfr[j], acc[i][j], 0, 0, 0);
        }

        // epilogue: bias, bf16 store, partial rowsum(exp) atomics
#pragma unroll
        for (int i = 0; i < 4; ++i) {
            float se[4] = {0.f, 0.f, 0.f, 0.f};
            int grow0 = m_tile * 128 + wm * 64 + i * 16 + kq * 4;   // + r
#pragma unroll
            for (int j = 0; j < 4; ++j) {
                int col = n_blk + n0 + j * 16 + l15;
#pragma unroll
                for (int r = 0; r < 4; ++r) {
                    float v = acc[i][j][r] + bj[j];
                    se[r] += __expf(v);
                    if (grow0 + r < Mdim)
                        logitsbf[(size_t)(grow0 + r) * Vdim + col] = f2bf(v);
                }
            }
#pragma unroll
            for (int r = 0; r < 4; ++r) {
#pragma unroll
                for (int off = 8; off; off >>= 1)
                    se[r] += __shfl_xor(se[r], off, 64);   // reduce over 16 cols (l15)
            }
            if (l15 == 0) {
#pragma unroll
                for (int r = 0; r < 4; ++r)
                    if (grow0 + r < Mdim) atomicAdd(&rowsum[grow0 + r], se[r]);
            }
        }
    }
}

// ---------------- combine: single-pass sparse scatter + log blend (128 KB LDS) ----------
__global__ __launch_bounds__(512) void combine_kernel(const unsigned short* __restrict__ logitsbf,
                                                      const float* __restrict__ weights,
                                                      const float* __restrict__ p_trans,
                                                      const float* __restrict__ trans_probs,
                                                      const float* __restrict__ probs,
                                                      const int* __restrict__ idxes,
                                                      const float* __restrict__ rowsum,
                                                      float* __restrict__ out) {
    __shared__ __align__(16) float ts[Vdim];               // 128000 bytes

    int bt = blockIdx.x;           // 0..799
    int b  = bt / Tdim;
    int tid = threadIdx.x;

    float pt = p_trans[bt];
    float c1 = (1.f - pt) / rowsum[bt];

    const short8* lrow8 = (const short8*)(logitsbf + (size_t)bt * Vdim);
    float4* out4 = (float4*)(out + (size_t)bt * Vdim);
    float4* ts4  = (float4*)ts;

    float4 z = make_float4(0.f, 0.f, 0.f, 0.f);
    for (int i = tid; i < Vdim / 4; i += 512) ts4[i] = z;
    __syncthreads();

    for (int i = tid; i < Sdim * Kk; i += 512) {
        float pv  = probs[b * (Sdim * Kk) + i];
        float tpv = trans_probs[b * (Sdim * Kk) + i];
        int   idx = idxes[b * (Sdim * Kk) + i];
        if (pv > 0.05f) {
            float w = weights[bt * Sdim + (i >> 3)];
            atomicAdd(&ts[idx], w * tpv);
        }
    }
    __syncthreads();

    for (int i = tid; i < Vdim / 8; i += 512) {
        short8 x8 = lrow8[i];
        float4 t0 = ts4[i * 2];
        float4 t1 = ts4[i * 2 + 1];
        float4 o0, o1;
        o0.x = __logf(pt * t0.x + c1 * __expf(bf2f((unsigned short)x8[0])));
        o0.y = __logf(pt * t0.y + c1 * __expf(bf2f((unsigned short)x8[1])));
        o0.z = __logf(pt * t0.z + c1 * __expf(bf2f((unsigned short)x8[2])));
        o0.w = __logf(pt * t0.w + c1 * __expf(bf2f((unsigned short)x8[3])));
        o1.x = __logf(pt * t1.x + c1 * __expf(bf2f((unsigned short)x8[4])));
        o1.y = __logf(pt * t1.y + c1 * __expf(bf2f((unsigned short)x8[5])));
        o1.z = __logf(pt * t1.z + c1 * __expf(bf2f((unsigned short)x8[6])));
        o1.w = __logf(pt * t1.w + c1 * __expf(bf2f((unsigned short)x8[7])));
        out4[i * 2]     = o0;
        out4[i * 2 + 1] = o1;
    }
}

extern "C" void kernel_launch(void* const* d_in, const int* in_sizes, int n_in,
                              void* d_out, int out_size, void* d_ws, size_t ws_size,
                              hipStream_t stream) {
    const float* dec_out     = (const float*)d_in[0];   // (8,100,512)
    const float* W           = (const float*)d_in[1];   // (512,32000)
    const float* bias        = (const float*)d_in[2];   // (32000,)
    const float* weights     = (const float*)d_in[3];   // (8,100,400)
    const float* p_trans     = (const float*)d_in[4];   // (8,100,1)
    const float* trans_probs = (const float*)d_in[5];   // (8,400,8)
    const float* probs       = (const float*)d_in[6];   // (8,400,8)
    const int*   idxes       = (const int*)d_in[7];     // (8,400,8)
    float* out = (float*)d_out;

    char* wsb = (char*)d_ws;
    unsigned short* Ap       = (unsigned short*)wsb;                      // 819,200 B (packed)
    unsigned short* WT       = (unsigned short*)(wsb + (1ull << 20));     // 32.8 MB
    unsigned short* logitsbf = (unsigned short*)(wsb + (35ull << 20));    // 51.2 MB
    float*          rowsum   = (float*)(wsb + (90ull << 20));             // 3200 B

    zero_kernel<<<dim3(4), dim3(256), 0, stream>>>(rowsum, Mdim);
    convert_a_kernel<<<dim3(200), dim3(256), 0, stream>>>(dec_out, Ap);
    transpose_kernel<<<dim3(Vdim / 32, Hdim / 32), dim3(256), 0, stream>>>(W, WT);
    gemm_kernel<<<dim3(Vdim / 128), dim3(256), 0, stream>>>(Ap, WT, bias, logitsbf, rowsum);
    combine_kernel<<<dim3(Mdim), dim3(512), 0, stream>>>(logitsbf, weights, p_trans, trans_probs,
                                                         probs, idxes, rowsum, out);
}

// Round 4
// 294.832 us; speedup vs baseline: 1.6212x; 1.6212x over previous
//
#include <hip/hip_runtime.h>

#define Bdim 8
#define Tdim 100
#define Sdim 400
#define Kk   8
#define Hdim 512
#define Vdim 32000
#define Mdim 800          // B*T
#define VHALF 16000

typedef __attribute__((ext_vector_type(8))) short short8;     // 8 bf16 = 4 VGPRs
typedef __attribute__((ext_vector_type(4))) float float4_t;   // MFMA acc

static __device__ __forceinline__ unsigned short f2bf(float f) {
    unsigned int x = __float_as_uint(f);
    return (unsigned short)((x + 0x7fffu + ((x >> 16) & 1u)) >> 16);   // RNE
}
static __device__ __forceinline__ float bf2f(unsigned short h) {
    return __uint_as_float(((unsigned int)h) << 16);
}

// async 16B global->LDS (wave-uniform LDS base + lane*16)
static __device__ __forceinline__ void gload_lds16(const void* g, void* s) {
    __builtin_amdgcn_global_load_lds((const __attribute__((address_space(1))) void*)g,
                                     (__attribute__((address_space(3))) void*)s, 16, 0, 0);
}

// ---------------- prep: dec_out fp32 -> bf16 packed fragment order; block 200 zeroes rowsum
// Ap[((mt*64 + kc)*16 + l15)*8 + j] = A[mt*16 + l15][kc*8 + j]
__global__ void convert_a_kernel(const float* __restrict__ A, unsigned short* __restrict__ Ap,
                                 float* __restrict__ rowsum) {
    if (blockIdx.x == 200) {
        for (int i = threadIdx.x; i < Mdim; i += 256) rowsum[i] = 0.f;
        return;
    }
    int tid = blockIdx.x * 256 + threadIdx.x;      // 0 .. 51199
    int mt = tid >> 10;
    int r  = tid & 1023;
    int kc = r >> 4;
    int l15 = r & 15;
    const float* src = A + (size_t)(mt * 16 + l15) * Hdim + kc * 8;
    short8 v;
#pragma unroll
    for (int j = 0; j < 8; ++j) v[j] = (short)f2bf(src[j]);
    *(short8*)(Ap + (size_t)tid * 8) = v;
}

// ---------------- prep: W (512 x 32000) fp32 -> WT (32000 x 512) bf16, 16B stores ----------
__global__ __launch_bounds__(256) void transpose_kernel(const float* __restrict__ W,
                                                        unsigned short* __restrict__ WT) {
    __shared__ float tile[32][65];
    int v0 = blockIdx.x * 64;
    int k0 = blockIdx.y * 32;
    int tx = threadIdx.x & 63;      // v
    int ty = threadIdx.x >> 6;      // 0..3
#pragma unroll
    for (int i = 0; i < 8; ++i)
        tile[ty + i * 4][tx] = W[(size_t)(k0 + ty + i * 4) * Vdim + v0 + tx];
    __syncthreads();
    int v  = threadIdx.x >> 2;          // 0..63
    int kc = (threadIdx.x & 3) * 8;     // 0,8,16,24
    short8 o;
#pragma unroll
    for (int j = 0; j < 8; ++j) o[j] = (short)f2bf(tile[kc + j][v]);
    *(short8*)(WT + (size_t)(v0 + v) * Hdim + k0 + kc) = o;
}

// ---------------- GEMM: logits = A * WT^T + bias (bf16 store) + row sumexp ----------------
// 1D grid 2048, swizzled so the 7 m-blocks of an n-stripe share id mod 8 (same XCD L2).
// Per kt: stage only B (16 KB, XOR-swizzled chunks) into double-buffered LDS; A fragments
// direct global->VGPR from packed Ap (L2-hot, coalesced). One barrier per kt.
__global__ __launch_bounds__(256) void gemm_kernel(const unsigned short* __restrict__ Ap,
                                                   const unsigned short* __restrict__ WT,
                                                   const float* __restrict__ bias,
                                                   unsigned short* __restrict__ logitsbf,
                                                   float* __restrict__ rowsum) {
    __shared__ __align__(16) unsigned short Bs[2 * 128 * 64];   // 2 x 16 KB

    const int id = blockIdx.x;
    const int xr = id & 7;
    const int t  = id >> 3;
    const int s  = ((t >> 3) << 3) | xr;    // n-stripe 0..255
    const int mb = t & 7;                   // m-tile 0..7
    if (s >= 250 || mb >= 7) return;

    const int tid  = threadIdx.x;
    const int lane = tid & 63;
    const int wave = tid >> 6;
    const int l15  = lane & 15;
    const int kq   = lane >> 4;             // 0..3
    const int m_blk = mb * 128;
    const int n_blk = s * 128;
    const int wm = wave & 1, wn = wave >> 1;
    const int n0 = wn * 64;

    // B staging: 1024 chunks/kt; thread handles q=0..3, chunk = q*256 + tid
    const unsigned short* bgp[4];
    int stg[4];
#pragma unroll
    for (int q = 0; q < 4; ++q) {
        int chunk = q * 256 + tid;
        int row = chunk >> 3, slot = chunk & 7;
        int gc = slot ^ (row & 7);
        bgp[q] = WT + (size_t)(n_blk + row) * Hdim + gc * 8;
        stg[q] = (q * 256 + wave * 64) * 8;          // wave-uniform LDS base (shorts)
    }

    // B fragment offsets (shorts): n*64 + ((ks*4+kq)^(n&7))*8, ks in {0,1}
    int eoff[2][4];
#pragma unroll
    for (int ks = 0; ks < 2; ++ks)
#pragma unroll
        for (int j = 0; j < 4; ++j) {
            int n = n0 + j * 16 + l15;
            eoff[ks][j] = n * 64 + (((ks * 4 + kq) ^ (n & 7)) * 8);
        }

    // A fragment pointers (packed layout)
    const unsigned short* ap[4];
#pragma unroll
    for (int i = 0; i < 4; ++i) {
        int mt = mb * 8 + wm * 4 + i;
        if (mt > 49) mt = 49;                        // clamp; stores masked
        ap[i] = Ap + (size_t)mt * 8192 + lane * 8;
    }

    float4_t acc[4][4] = {};

    // stage kt=0
#pragma unroll
    for (int q = 0; q < 4; ++q) gload_lds16(bgp[q], Bs + stg[q]);
    __syncthreads();

    for (int kt = 0; kt < 8; ++kt) {
        if (kt + 1 < 8) {
            const unsigned short* nb = Bs + ((kt + 1) & 1) * 8192;
#pragma unroll
            for (int q = 0; q < 4; ++q)
                gload_lds16(bgp[q] + (kt + 1) * 64, (void*)(nb + stg[q]));
        }
        const unsigned short* cb = Bs + (kt & 1) * 8192;
#pragma unroll
        for (int ks = 0; ks < 2; ++ks) {
            const int kcg = kt * 2 + ks;
            short8 af[4], bfr[4];
#pragma unroll
            for (int i = 0; i < 4; ++i) af[i]  = *(const short8*)(ap[i] + kcg * 512);
#pragma unroll
            for (int j = 0; j < 4; ++j) bfr[j] = *(const short8*)(cb + eoff[ks][j]);
#pragma unroll
            for (int i = 0; i < 4; ++i)
#pragma unroll
                for (int j = 0; j < 4; ++j)
                    acc[i][j] = __builtin_amdgcn_mfma_f32_16x16x32_bf16(af[i], bfr[j], acc[i][j], 0, 0, 0);
        }
        __syncthreads();    // vmcnt(0) drain => stage(kt+1) complete; Bs[cur] free for kt+2
    }

    // epilogue: bias, bf16 store, partial rowsum(exp) atomics
    float bj[4];
#pragma unroll
    for (int j = 0; j < 4; ++j) bj[j] = bias[n_blk + n0 + j * 16 + l15];

#pragma unroll
    for (int i = 0; i < 4; ++i) {
        float se[4] = {0.f, 0.f, 0.f, 0.f};
        int grow0 = m_blk + wm * 64 + i * 16 + kq * 4;      // + r
#pragma unroll
        for (int j = 0; j < 4; ++j) {
            int col = n_blk + n0 + j * 16 + l15;
#pragma unroll
            for (int r = 0; r < 4; ++r) {
                float v = acc[i][j][r] + bj[j];
                se[r] += __expf(v);
                if (grow0 + r < Mdim)
                    logitsbf[(size_t)(grow0 + r) * Vdim + col] = f2bf(v);
            }
        }
#pragma unroll
        for (int r = 0; r < 4; ++r) {
#pragma unroll
            for (int off = 8; off; off >>= 1)
                se[r] += __shfl_xor(se[r], off, 64);   // reduce over 16 cols (l15)
        }
        if (l15 == 0) {
#pragma unroll
            for (int r = 0; r < 4; ++r)
                if (grow0 + r < Mdim) atomicAdd(&rowsum[grow0 + r], se[r]);
        }
    }
}

// ---------------- combine: sparse scatter + log blend; grid (800, 2) over V-halves -------
__global__ __launch_bounds__(512) void combine_kernel(const unsigned short* __restrict__ logitsbf,
                                                      const float* __restrict__ weights,
                                                      const float* __restrict__ p_trans,
                                                      const float* __restrict__ trans_probs,
                                                      const float* __restrict__ probs,
                                                      const int* __restrict__ idxes,
                                                      const float* __restrict__ rowsum,
                                                      float* __restrict__ out) {
    __shared__ __align__(16) float ts[VHALF];      // 64 KB

    int bt = blockIdx.x;           // 0..799
    int h  = blockIdx.y;           // 0..1
    int b  = bt / Tdim;
    int tid = threadIdx.x;

    float pt = p_trans[bt];
    float c1 = (1.f - pt) / rowsum[bt];

    const short8* lrow8 = (const short8*)(logitsbf + (size_t)bt * Vdim);
    float4* out4 = (float4*)(out + (size_t)bt * Vdim);
    float4* ts4  = (float4*)ts;

    float4 z = make_float4(0.f, 0.f, 0.f, 0.f);
    for (int i = tid; i < VHALF / 4; i += 512) ts4[i] = z;
    __syncthreads();

    for (int i = tid; i < Sdim * Kk; i += 512) {
        float pv  = probs[b * (Sdim * Kk) + i];
        float tpv = trans_probs[b * (Sdim * Kk) + i];
        int   idx = idxes[b * (Sdim * Kk) + i];
        int   rel = idx - h * VHALF;
        if (pv > 0.05f && (unsigned)rel < (unsigned)VHALF) {
            float w = weights[bt * Sdim + (i >> 3)];
            atomicAdd(&ts[rel], w * tpv);
        }
    }
    __syncthreads();

    for (int i = tid; i < VHALF / 8; i += 512) {
        short8 x8 = lrow8[h * (VHALF / 8) + i];
        float4 t0 = ts4[i * 2];
        float4 t1 = ts4[i * 2 + 1];
        float4 o0, o1;
        o0.x = __logf(pt * t0.x + c1 * __expf(bf2f((unsigned short)x8[0])));
        o0.y = __logf(pt * t0.y + c1 * __expf(bf2f((unsigned short)x8[1])));
        o0.z = __logf(pt * t0.z + c1 * __expf(bf2f((unsigned short)x8[2])));
        o0.w = __logf(pt * t0.w + c1 * __expf(bf2f((unsigned short)x8[3])));
        o1.x = __logf(pt * t1.x + c1 * __expf(bf2f((unsigned short)x8[4])));
        o1.y = __logf(pt * t1.y + c1 * __expf(bf2f((unsigned short)x8[5])));
        o1.z = __logf(pt * t1.z + c1 * __expf(bf2f((unsigned short)x8[6])));
        o1.w = __logf(pt * t1.w + c1 * __expf(bf2f((unsigned short)x8[7])));
        out4[h * (VHALF / 4) + i * 2]     = o0;
        out4[h * (VHALF / 4) + i * 2 + 1] = o1;
    }
}

extern "C" void kernel_launch(void* const* d_in, const int* in_sizes, int n_in,
                              void* d_out, int out_size, void* d_ws, size_t ws_size,
                              hipStream_t stream) {
    const float* dec_out     = (const float*)d_in[0];   // (8,100,512)
    const float* W           = (const float*)d_in[1];   // (512,32000)
    const float* bias        = (const float*)d_in[2];   // (32000,)
    const float* weights     = (const float*)d_in[3];   // (8,100,400)
    const float* p_trans     = (const float*)d_in[4];   // (8,100,1)
    const float* trans_probs = (const float*)d_in[5];   // (8,400,8)
    const float* probs       = (const float*)d_in[6];   // (8,400,8)
    const int*   idxes       = (const int*)d_in[7];     // (8,400,8)
    float* out = (float*)d_out;

    char* wsb = (char*)d_ws;
    unsigned short* Ap       = (unsigned short*)wsb;                      // 819,200 B (packed)
    unsigned short* WT       = (unsigned short*)(wsb + (1ull << 20));     // 32.8 MB
    unsigned short* logitsbf = (unsigned short*)(wsb + (35ull << 20));    // 51.2 MB
    float*          rowsum   = (float*)(wsb + (90ull << 20));             // 3200 B

    convert_a_kernel<<<dim3(201), dim3(256), 0, stream>>>(dec_out, Ap, rowsum);
    transpose_kernel<<<dim3(Vdim / 64, Hdim / 32), dim3(256), 0, stream>>>(W, WT);
    gemm_kernel<<<dim3(2048), dim3(256), 0, stream>>>(Ap, WT, bias, logitsbf, rowsum);
    combine_kernel<<<dim3(Mdim, 2), dim3(512), 0, stream>>>(logitsbf, weights, p_trans, trans_probs,
                                                            probs, idxes, rowsum, out);
}